// Round 1
// baseline (314.814 us; speedup 1.0000x reference)
//
#include <hip/hip_runtime.h>
#include <hip/hip_bf16.h>
#include <stdint.h>

// Problem constants
#define NT 4096      // tokens
#define DM 320       // model dim
#define NH 8         // heads
#define DH 40        // head dim
#define DHP 64       // padded head dim for Q/K (zero-padded; MFMA K=32 x2)
#define DVP 48       // padded head dim rows for V^T (cols >=40 discarded)
#define SCALE 0.15811388300841898f  // 1/sqrt(40)

typedef float f32x4 __attribute__((ext_vector_type(4)));
typedef __bf16 bf16x8 __attribute__((ext_vector_type(8)));

__device__ __forceinline__ unsigned short f2b(float f) {
  unsigned u = __builtin_bit_cast(unsigned, f);
  u += 0x7FFFu + ((u >> 16) & 1u);   // RNE
  return (unsigned short)(u >> 16);
}

__device__ __forceinline__ bf16x8 ld_bf8(const unsigned short* p) {
  uint4 v = *(const uint4*)p;        // 16B load
  return __builtin_bit_cast(bf16x8, v);
}

__device__ __forceinline__ f32x4 mfma16(bf16x8 a, bf16x8 b, f32x4 c) {
  return __builtin_amdgcn_mfma_f32_16x16x32_bf16(a, b, c, 0, 0, 0);
}

// ---------------- kernel 1: phase signatures ----------------
__global__ __launch_bounds__(256) void sig_kernel(const float* __restrict__ g,
                                                  unsigned* __restrict__ sig) {
  int i = blockIdx.x * 256 + threadIdx.x;
  if (i < NT) {
    unsigned s = 0;
    if (g[i] != 0.f)          s |= 1u;
    if (g[NT + i] != 0.f)     s |= 2u;
    if (g[2 * NT + i] != 0.f) s |= 4u;
    sig[i] = s;
  }
}

// ---------------- kernel 2: fused QKV projection ----------------
// C[m][c] = sum_k x[m][k] * W[k][c];  c in [0,960) across {Wq,Wk,Wv}
// Q,K stored [h][n][DHP] bf16 (cols 40..63 pre-zeroed);
// V stored transposed [h][DVP][n] bf16 (rows 40..47 pre-zeroed).
__global__ __launch_bounds__(256) void qkv_gemm(
    const float* __restrict__ x, const float* __restrict__ Wq,
    const float* __restrict__ Wk, const float* __restrict__ Wv,
    unsigned short* __restrict__ Qb, unsigned short* __restrict__ Kb,
    unsigned short* __restrict__ Vtb) {
  __shared__ __align__(16) unsigned short xt[64 * 40];  // [m][k] pad 40
  __shared__ __align__(16) unsigned short wt[64 * 40];  // [c][k] pad 40
  const int t = threadIdx.x;
  const int w = t >> 6, lane = t & 63, quad = lane >> 4, ln = lane & 15;
  const int m0 = blockIdx.x * 64;
  const int a = blockIdx.y / 5;              // 0=Q 1=K 2=V
  const int cc0 = (blockIdx.y % 5) * 64;     // col within the 320-wide matrix
  const float* W = (a == 0) ? Wq : ((a == 1) ? Wk : Wv);

  f32x4 acc[4] = {{0,0,0,0},{0,0,0,0},{0,0,0,0},{0,0,0,0}};
  for (int kc = 0; kc < 10; ++kc) {
    __syncthreads();
#pragma unroll
    for (int i = 0; i < 8; ++i) {            // x tile 64x32
      int row = (t >> 5) + i * 8, col = t & 31;
      xt[row * 40 + col] = f2b(x[(m0 + row) * DM + kc * 32 + col]);
    }
#pragma unroll
    for (int i = 0; i < 8; ++i) {            // W^T tile 64x32
      int kk = (t >> 6) + i * 4, c = t & 63;
      wt[c * 40 + kk] = f2b(W[(kc * 32 + kk) * DM + cc0 + c]);
    }
    __syncthreads();
    bf16x8 af = ld_bf8(&xt[(w * 16 + ln) * 40 + quad * 8]);
#pragma unroll
    for (int nt = 0; nt < 4; ++nt) {
      bf16x8 bf = ld_bf8(&wt[(nt * 16 + ln) * 40 + quad * 8]);
      acc[nt] = mfma16(af, bf, acc[nt]);
    }
  }
#pragma unroll
  for (int nt = 0; nt < 4; ++nt) {
#pragma unroll
    for (int r = 0; r < 4; ++r) {
      int row = m0 + w * 16 + quad * 4 + r;  // D row = quad*4+reg
      int cc = cc0 + nt * 16 + ln;           // D col = lane&15
      int h = cc / DH, d = cc % DH;
      unsigned short v = f2b(acc[nt][r]);
      if (a < 2) {
        unsigned short* dst = (a == 0) ? Qb : Kb;
        dst[((size_t)(h * NT + row)) * DHP + d] = v;
      } else {
        Vtb[((size_t)(h * DVP + d)) * NT + row] = v;
      }
    }
  }
}

// ---------------- kernel 3: masked flash attention ----------------
// grid (64 q-tiles, 8 heads); block 256 = 4 waves x 16 Q-rows.
__global__ __launch_bounds__(256) void attn_kernel(
    const unsigned short* __restrict__ Qb, const unsigned short* __restrict__ Kb,
    const unsigned short* __restrict__ Vtb, const unsigned* __restrict__ sig,
    unsigned short* __restrict__ Ob) {
  __shared__ __align__(16) unsigned short kt[64 * 72];      // K tile [j][d] pad 72
  __shared__ __align__(16) unsigned short vt[48 * 72];      // V^T tile [d][j] pad 72
  __shared__ __align__(16) unsigned short pt[4][16 * 72];   // per-wave P [m][j]
  const int t = threadIdx.x;
  const int w = t >> 6, lane = t & 63, quad = lane >> 4, ln = lane & 15;
  const int h = blockIdx.y, qt = blockIdx.x;
  const int qrow = qt * 64 + w * 16;

  const unsigned short* Qh = Qb + ((size_t)(h * NT + qrow + ln)) * DHP;
  bf16x8 qa0 = ld_bf8(Qh + quad * 8);        // A[m=ln][k=quad*8+j], k 0..31
  bf16x8 qa1 = ld_bf8(Qh + 32 + quad * 8);   // k 32..63 (40..63 zero)

  unsigned sq[4];
  float mrun[4], lrun[4];
  f32x4 o[3] = {{0,0,0,0},{0,0,0,0},{0,0,0,0}};
#pragma unroll
  for (int r = 0; r < 4; ++r) {
    sq[r] = sig[qrow + quad * 4 + r];
    mrun[r] = -3e38f; lrun[r] = 0.f;
  }
  const unsigned short* Ksrc0 = Kb + ((size_t)h * NT) * DHP;
  const unsigned short* Vsrc0 = Vtb + (size_t)h * DVP * NT;

  for (int jt = 0; jt < 64; ++jt) {
    __syncthreads();
#pragma unroll
    for (int i = 0; i < 2; ++i) {            // stage K tile: 512 x 16B
      int idx = t + i * 256;
      int r = idx >> 3, c8 = idx & 7;
      *(uint4*)&kt[r * 72 + c8 * 8] = *(const uint4*)&Ksrc0[(jt * 64 + r) * DHP + c8 * 8];
    }
#pragma unroll
    for (int i = 0; i < 2; ++i) {            // stage V^T tile: 384 x 16B
      int idx = t + i * 256;
      if (idx < 384) {
        int r = idx >> 3, c8 = idx & 7;
        *(uint4*)&vt[r * 72 + c8 * 8] = *(const uint4*)&Vsrc0[(size_t)r * NT + jt * 64 + c8 * 8];
      }
    }
    __syncthreads();

    float lg[4][4], ps[4][4];
    bool pf[4][4];
    unsigned sk[4];
#pragma unroll
    for (int nt = 0; nt < 4; ++nt) {
      bf16x8 kb0 = ld_bf8(&kt[(nt * 16 + ln) * 72 + quad * 8]);
      bf16x8 kb1 = ld_bf8(&kt[(nt * 16 + ln) * 72 + 32 + quad * 8]);
      f32x4 acc = {0, 0, 0, 0};
      acc = mfma16(qa0, kb0, acc);
      acc = mfma16(qa1, kb1, acc);
      sk[nt] = sig[jt * 64 + nt * 16 + ln];
#pragma unroll
      for (int r = 0; r < 4; ++r) {
        bool uni = (sq[r] == 0u);                        // fully-masked row -> uniform
        bool um = uni || ((sq[r] & sk[nt]) != 0u);
        lg[nt][r] = um ? (uni ? 0.f : acc[r] * SCALE) : -3e38f;
        pf[nt][r] = um;
      }
    }
    float alpha[4], mnew[4];
#pragma unroll
    for (int r = 0; r < 4; ++r) {
      float v = fmaxf(fmaxf(lg[0][r], lg[1][r]), fmaxf(lg[2][r], lg[3][r]));
      v = fmaxf(v, __shfl_xor(v, 1, 16));
      v = fmaxf(v, __shfl_xor(v, 2, 16));
      v = fmaxf(v, __shfl_xor(v, 4, 16));
      v = fmaxf(v, __shfl_xor(v, 8, 16));
      mnew[r] = fmaxf(mrun[r], v);
      alpha[r] = __expf(mrun[r] - mnew[r]);
      mrun[r] = mnew[r];
    }
    float rs[4] = {0, 0, 0, 0};
#pragma unroll
    for (int nt = 0; nt < 4; ++nt)
#pragma unroll
      for (int r = 0; r < 4; ++r) {
        float p = pf[nt][r] ? __expf(lg[nt][r] - mnew[r]) : 0.f;
        ps[nt][r] = p;
        rs[r] += p;
      }
#pragma unroll
    for (int r = 0; r < 4; ++r) {
      float s = rs[r];
      s += __shfl_xor(s, 1, 16);
      s += __shfl_xor(s, 2, 16);
      s += __shfl_xor(s, 4, 16);
      s += __shfl_xor(s, 8, 16);
      lrun[r] = lrun[r] * alpha[r] + s;
      o[0][r] *= alpha[r]; o[1][r] *= alpha[r]; o[2][r] *= alpha[r];
    }
    // P: D-layout (row=quad*4+reg, col=lane&15) -> LDS -> A-layout
    unsigned short* ptw = pt[w];
#pragma unroll
    for (int nt = 0; nt < 4; ++nt)
#pragma unroll
      for (int r = 0; r < 4; ++r)
        ptw[(quad * 4 + r) * 72 + nt * 16 + ln] = f2b(ps[nt][r]);
    asm volatile("s_waitcnt lgkmcnt(0)" ::: "memory");   // wave-internal LDS WAR/RAW
    bf16x8 pa0 = ld_bf8(&ptw[ln * 72 + quad * 8]);
    bf16x8 pa1 = ld_bf8(&ptw[ln * 72 + 32 + quad * 8]);
#pragma unroll
    for (int ot = 0; ot < 3; ++ot) {
      bf16x8 vb0 = ld_bf8(&vt[(ot * 16 + ln) * 72 + quad * 8]);
      bf16x8 vb1 = ld_bf8(&vt[(ot * 16 + ln) * 72 + 32 + quad * 8]);
      o[ot] = mfma16(pa0, vb0, o[ot]);
      o[ot] = mfma16(pa1, vb1, o[ot]);
    }
  }
#pragma unroll
  for (int r = 0; r < 4; ++r) {
    float inv = 1.f / lrun[r];
    int row = qrow + quad * 4 + r;
#pragma unroll
    for (int ot = 0; ot < 3; ++ot) {
      int col = ot * 16 + ln;
      if (col < DH)
        Ob[(size_t)row * DM + h * DH + col] = f2b(o[ot][r] * inv);
    }
  }
}

// ---------------- kernel 4: output projection + bias ----------------
__global__ __launch_bounds__(256) void out_gemm(
    const unsigned short* __restrict__ Ob, const float* __restrict__ Wo,
    const float* __restrict__ bo, float* __restrict__ out) {
  __shared__ __align__(16) unsigned short at[64 * 40];
  __shared__ __align__(16) unsigned short wt[64 * 40];
  const int t = threadIdx.x;
  const int w = t >> 6, lane = t & 63, quad = lane >> 4, ln = lane & 15;
  const int m0 = blockIdx.x * 64;
  const int c0 = blockIdx.y * 64;
  f32x4 acc[4] = {{0,0,0,0},{0,0,0,0},{0,0,0,0},{0,0,0,0}};
  for (int kc = 0; kc < 10; ++kc) {
    __syncthreads();
    {
      int r = t >> 2, c8 = t & 3;            // O tile 64x32 bf16, 16B chunks
      *(uint4*)&at[r * 40 + c8 * 8] = *(const uint4*)&Ob[(size_t)(m0 + r) * DM + kc * 32 + c8 * 8];
    }
#pragma unroll
    for (int i = 0; i < 8; ++i) {            // Wo^T tile
      int kk = (t >> 6) + i * 4, c = t & 63;
      wt[c * 40 + kk] = f2b(Wo[(kc * 32 + kk) * DM + c0 + c]);
    }
    __syncthreads();
    bf16x8 af = ld_bf8(&at[(w * 16 + ln) * 40 + quad * 8]);
#pragma unroll
    for (int nt = 0; nt < 4; ++nt) {
      bf16x8 bf = ld_bf8(&wt[(nt * 16 + ln) * 40 + quad * 8]);
      acc[nt] = mfma16(af, bf, acc[nt]);
    }
  }
#pragma unroll
  for (int nt = 0; nt < 4; ++nt)
#pragma unroll
    for (int r = 0; r < 4; ++r) {
      int row = m0 + w * 16 + quad * 4 + r;
      int col = c0 + nt * 16 + ln;
      out[(size_t)row * DM + col] = acc[nt][r] + bo[col];
    }
}

// ---------------- launcher ----------------
extern "C" void kernel_launch(void* const* d_in, const int* in_sizes, int n_in,
                              void* d_out, int out_size, void* d_ws, size_t ws_size,
                              hipStream_t stream) {
  const float* x  = (const float*)d_in[0];
  const float* g  = (const float*)d_in[1];
  const float* Wq = (const float*)d_in[2];
  const float* Wk = (const float*)d_in[3];
  const float* Wv = (const float*)d_in[4];
  const float* Wo = (const float*)d_in[5];
  const float* bo = (const float*)d_in[6];
  float* out = (float*)d_out;

  char* ws = (char*)d_ws;
  const size_t SIG_OFF = 0;
  const size_t QB_OFF  = 16384;
  const size_t KB_OFF  = QB_OFF + (size_t)NH * NT * DHP * 2;   // +4 MiB
  const size_t VT_OFF  = KB_OFF + (size_t)NH * NT * DHP * 2;   // +4 MiB
  const size_t OB_OFF  = VT_OFF + (size_t)NH * DVP * NT * 2;   // +3 MiB
  unsigned* sig        = (unsigned*)(ws + SIG_OFF);
  unsigned short* Qb   = (unsigned short*)(ws + QB_OFF);
  unsigned short* Kb   = (unsigned short*)(ws + KB_OFF);
  unsigned short* Vtb  = (unsigned short*)(ws + VT_OFF);
  unsigned short* Ob   = (unsigned short*)(ws + OB_OFF);

  // zero Q/K pad cols and V^T pad rows (ws is poisoned before every launch)
  hipMemsetAsync(ws + QB_OFF, 0, OB_OFF - QB_OFF, stream);

  sig_kernel<<<16, 256, 0, stream>>>(g, sig);
  qkv_gemm<<<dim3(64, 15), 256, 0, stream>>>(x, Wq, Wk, Wv, Qb, Kb, Vtb);
  attn_kernel<<<dim3(64, 8), 256, 0, stream>>>(Qb, Kb, Vtb, sig, Ob);
  out_gemm<<<dim3(64, 5), 256, 0, stream>>>(Ob, Wo, bo, out);
}